// Round 2
// baseline (180.906 us; speedup 1.0000x reference)
//
#include <hip/hip_runtime.h>
#include <math.h>

constexpr int NB = 1024;  // batch
constexpr int NT = 256;   // topic_size
constexpr int NE = 300;   // embedding_size
constexpr int NBATCH = 4; // batches per k_main block

#if defined(__has_builtin)
#if __has_builtin(__builtin_amdgcn_exp2f)
#define EXP2F(x) __builtin_amdgcn_exp2f(x)
#else
#define EXP2F(x) exp2f(x)
#endif
#if __has_builtin(__builtin_amdgcn_logf)
#define LOG2F(x) __builtin_amdgcn_logf(x)
#else
#define LOG2F(x) log2f(x)
#endif
#else
#define EXP2F(x) exp2f(x)
#define LOG2F(x) log2f(x)
#endif

__device__ __forceinline__ float frag_get(const float4& v, int k) {
  return k == 0 ? v.x : k == 1 ? v.y : k == 2 ? v.z : v.w;
}

// M[t,f] = sum_e TE[e,t] * wf[f,e].  64x64 tiles, 256 thr, 4x4 utile. grid 16.
__global__ __launch_bounds__(256) void k_M(const float* __restrict__ TE,
                                           const float* __restrict__ wf,
                                           float* __restrict__ M) {
  __shared__ __align__(16) float At[64][33];  // [t][e]
  __shared__ __align__(16) float Bt[64][33];  // [f][e]
  int tid = threadIdx.x;
  int t0 = (blockIdx.x >> 2) * 64, f0 = (blockIdx.x & 3) * 64;
  int ty = tid >> 4, tx = tid & 15;
  float acc[4][4] = {};
  for (int e0 = 0; e0 < NE; e0 += 32) {
    __syncthreads();
    for (int idx = tid; idx < 32 * 64; idx += 256) {
      int ee = idx >> 6, tt = idx & 63;  // coalesced in tt
      At[tt][ee] = (e0 + ee < NE) ? TE[(e0 + ee) * NT + t0 + tt] : 0.f;
    }
    for (int idx = tid; idx < 32 * 64; idx += 256) {
      int ee = idx & 31, ff = idx >> 5;  // coalesced in ee
      Bt[ff][ee] = (e0 + ee < NE) ? wf[(f0 + ff) * NE + e0 + ee] : 0.f;
    }
    __syncthreads();
    for (int ee = 0; ee < 32; ++ee) {
      float a[4], b[4];
#pragma unroll
      for (int r = 0; r < 4; ++r) a[r] = At[ty * 4 + r][ee];
#pragma unroll
      for (int s = 0; s < 4; ++s) b[s] = Bt[tx * 4 + s][ee];
#pragma unroll
      for (int r = 0; r < 4; ++r)
#pragma unroll
        for (int s = 0; s < 4; ++s) acc[r][s] = fmaf(a[r], b[s], acc[r][s]);
    }
  }
#pragma unroll
  for (int r = 0; r < 4; ++r)
    *(float4*)&M[(t0 + ty * 4 + r) * NT + f0 + tx * 4] =
        make_float4(acc[r][0], acc[r][1], acc[r][2], acc[r][3]);
}

// blocks 0..15: G2 = (M M^T) * log2(e).  block 16: u2 = (M b_f) * log2(e).
__global__ __launch_bounds__(256) void k_G(const float* __restrict__ Mm,
                                           const float* __restrict__ bf,
                                           float* __restrict__ G2,
                                           float* __restrict__ u2) {
  __shared__ __align__(16) float At[64][33];
  __shared__ __align__(16) float Bt[64][33];
  const float LOG2E = 1.4426950408889634f;
  int tid = threadIdx.x;
  if (blockIdx.x == 16) {  // u2
    int wv = tid >> 6, ln = tid & 63;
    for (int i = wv; i < NT; i += 4) {
      float p = 0.f;
#pragma unroll
      for (int kk = 0; kk < 4; ++kk) {
        int k = ln + kk * 64;
        p = fmaf(Mm[i * NT + k], bf[k], p);
      }
#pragma unroll
      for (int off = 32; off > 0; off >>= 1) p += __shfl_down(p, off, 64);
      if (ln == 0) u2[i] = p * LOG2E;
    }
    return;
  }
  int i0 = (blockIdx.x >> 2) * 64, j0 = (blockIdx.x & 3) * 64;
  int ty = tid >> 4, tx = tid & 15;
  float acc[4][4] = {};
  for (int k0 = 0; k0 < NT; k0 += 32) {
    __syncthreads();
    for (int idx = tid; idx < 64 * 32; idx += 256) {
      int ii = idx >> 5, kk = idx & 31;  // coalesced in kk
      At[ii][kk] = Mm[(i0 + ii) * NT + k0 + kk];
      Bt[ii][kk] = Mm[(j0 + ii) * NT + k0 + kk];
    }
    __syncthreads();
    for (int kk = 0; kk < 32; ++kk) {
      float a[4], b[4];
#pragma unroll
      for (int r = 0; r < 4; ++r) a[r] = At[ty * 4 + r][kk];
#pragma unroll
      for (int s = 0; s < 4; ++s) b[s] = Bt[tx * 4 + s][kk];
#pragma unroll
      for (int r = 0; r < 4; ++r)
#pragma unroll
        for (int s = 0; s < 4; ++s) acc[r][s] = fmaf(a[r], b[s], acc[r][s]);
    }
  }
#pragma unroll
  for (int r = 0; r < 4; ++r)
    *(float4*)&G2[(i0 + ty * 4 + r) * NT + j0 + tx * 4] =
        make_float4(acc[r][0] * LOG2E, acc[r][1] * LOG2E, acc[r][2] * LOG2E,
                    acc[r][3] * LOG2E);
}

// 4 batches per block; block = 1024 = 4 quads x 256 columns. Quad q covers
// i in [64q, 64q+64). All loop-indexed r/w/u reads use wave-uniform indices
// -> scalar loads (no LDS pipe). Softmax state folded to L = m + log2(d).
__global__ __launch_bounds__(1024) void k_main(
    const float* __restrict__ req, const float* __restrict__ wsdl,
    const float* __restrict__ Mm, const float* __restrict__ G2,
    const float* __restrict__ u2, const float* __restrict__ bf,
    float* __restrict__ out) {
  __shared__ __align__(16) float L_s[NT][4];
  __shared__ __align__(16) float qv_s[NT][4];
  __shared__ __align__(16) float red[4][NT][8];
  __shared__ float fin[16][12];

  int tid = threadIdx.x;
  int q = __builtin_amdgcn_readfirstlane(tid >> 8);  // wave-uniform quad id
  int c = tid & 255;
  int i0 = q * 64;
  int b0 = blockIdx.x * NBATCH;

  // ---- Phase A pass 1: per-column max over this quad's i-range ----
  float wb[NBATCH], m_loc[NBATCH];
#pragma unroll
  for (int bb = 0; bb < NBATCH; ++bb) {
    wb[bb] = wsdl[(b0 + bb) * NT + c];
    m_loc[bb] = -3.0e38f;
  }
#pragma unroll 8
  for (int ii = 0; ii < 64; ++ii) {
    int i = i0 + ii;
    float g = G2[i * NT + c];  // coalesced
    float su = u2[i];          // uniform -> s_load
#pragma unroll
    for (int bb = 0; bb < NBATCH; ++bb) {
      float sr = req[(b0 + bb) * NT + i];  // uniform -> s_load
      float h = fmaf(wb[bb], g, su);
      m_loc[bb] = fmaxf(m_loc[bb], sr * h);
    }
  }
  *(float4*)&red[q][c][0] = make_float4(m_loc[0], m_loc[1], m_loc[2], m_loc[3]);
  __syncthreads();
  float m_full[NBATCH];
  {
    float4 r0 = *(float4*)&red[0][c][0], r1 = *(float4*)&red[1][c][0];
    float4 r2 = *(float4*)&red[2][c][0], r3 = *(float4*)&red[3][c][0];
    m_full[0] = fmaxf(fmaxf(r0.x, r1.x), fmaxf(r2.x, r3.x));
    m_full[1] = fmaxf(fmaxf(r0.y, r1.y), fmaxf(r2.y, r3.y));
    m_full[2] = fmaxf(fmaxf(r0.z, r1.z), fmaxf(r2.z, r3.z));
    m_full[3] = fmaxf(fmaxf(r0.w, r1.w), fmaxf(r2.w, r3.w));
  }
  __syncthreads();

  // ---- Phase A pass 2: denominators; L = m + log2(d) ----
  float d_loc[NBATCH] = {0.f, 0.f, 0.f, 0.f};
#pragma unroll 8
  for (int ii = 0; ii < 64; ++ii) {
    int i = i0 + ii;
    float g = G2[i * NT + c];
    float su = u2[i];
#pragma unroll
    for (int bb = 0; bb < NBATCH; ++bb) {
      float sr = req[(b0 + bb) * NT + i];
      float h = fmaf(wb[bb], g, su);
      d_loc[bb] += EXP2F(fmaf(sr, h, -m_full[bb]));
    }
  }
  *(float4*)&red[q][c][0] = make_float4(d_loc[0], d_loc[1], d_loc[2], d_loc[3]);
  __syncthreads();
  {
    float4 r0 = *(float4*)&red[0][c][0], r1 = *(float4*)&red[1][c][0];
    float4 r2 = *(float4*)&red[2][c][0], r3 = *(float4*)&red[3][c][0];
    if (q == 0) {
      float4 L4;
      L4.x = m_full[0] + LOG2F(r0.x + r1.x + r2.x + r3.x);
      L4.y = m_full[1] + LOG2F(r0.y + r1.y + r2.y + r3.y);
      L4.z = m_full[2] + LOG2F(r0.z + r1.z + r2.z + r3.z);
      L4.w = m_full[3] + LOG2F(r0.w + r1.w + r2.w + r3.w);
      *(float4*)&L_s[c][0] = L4;
    }
  }
  __syncthreads();

  // ---- Phase S: row-sums of softmaxed att (row i = c), j over quad range ----
  float rc[NBATCH], Sp[NBATCH] = {0.f, 0.f, 0.f, 0.f};
#pragma unroll
  for (int bb = 0; bb < NBATCH; ++bb) rc[bb] = req[(b0 + bb) * NT + c];
  float uc = u2[c];
#pragma unroll 8
  for (int jj = 0; jj < 64; ++jj) {
    int j = i0 + jj;
    float g = G2[j * NT + c];  // = G2[c][j] by symmetry; coalesced
    float4 Lj = *(const float4*)&L_s[j][0];  // single b128 broadcast per j
#pragma unroll
    for (int bb = 0; bb < NBATCH; ++bb) {
      float sw = wsdl[(b0 + bb) * NT + j];  // uniform -> s_load
      float h = fmaf(sw, g, uc);
      Sp[bb] += EXP2F(fmaf(rc[bb], h, -frag_get(Lj, bb)));
    }
  }
  *(float4*)&red[q][c][0] = make_float4(Sp[0], Sp[1], Sp[2], Sp[3]);
  __syncthreads();
  {
    float4 r0 = *(float4*)&red[0][c][0], r1 = *(float4*)&red[1][c][0];
    float4 r2 = *(float4*)&red[2][c][0], r3 = *(float4*)&red[3][c][0];
    if (q == 0) {
      float4 qv;
      qv.x = (r0.x + r1.x + r2.x + r3.x) * rc[0];
      qv.y = (r0.y + r1.y + r2.y + r3.y) * rc[1];
      qv.z = (r0.z + r1.z + r2.z + r3.z) * rc[2];
      qv.w = (r0.w + r1.w + r2.w + r3.w) * rc[3];
      *(float4*)&qv_s[c][0] = qv;
    }
  }
  __syncthreads();

  // ---- Phase B: ave_req = (r/T)@M + bf, ave_wsdl = (qv/T)@M + bf ----
  float ar[NBATCH] = {0.f, 0.f, 0.f, 0.f}, aw[NBATCH] = {0.f, 0.f, 0.f, 0.f};
#pragma unroll 4
  for (int tt = 0; tt < 64; ++tt) {
    int t = i0 + tt;
    float mk = Mm[t * NT + c];  // coalesced
    float4 qv4 = *(const float4*)&qv_s[t][0];
#pragma unroll
    for (int bb = 0; bb < NBATCH; ++bb) {
      float sr = req[(b0 + bb) * NT + t];  // uniform -> s_load
      ar[bb] = fmaf(sr, mk, ar[bb]);
      aw[bb] = fmaf(frag_get(qv4, bb), mk, aw[bb]);
    }
  }
  *(float4*)&red[q][c][0] = make_float4(ar[0], ar[1], ar[2], ar[3]);
  *(float4*)&red[q][c][4] = make_float4(aw[0], aw[1], aw[2], aw[3]);
  __syncthreads();
  float st[12];
  {
    float4 a0 = *(float4*)&red[0][c][0], a1 = *(float4*)&red[1][c][0];
    float4 a2 = *(float4*)&red[2][c][0], a3 = *(float4*)&red[3][c][0];
    float4 w0 = *(float4*)&red[0][c][4], w1 = *(float4*)&red[1][c][4];
    float4 w2 = *(float4*)&red[2][c][4], w3 = *(float4*)&red[3][c][4];
    float bfc = bf[c];
    float arT[4], awT[4];
    arT[0] = a0.x + a1.x + a2.x + a3.x; awT[0] = w0.x + w1.x + w2.x + w3.x;
    arT[1] = a0.y + a1.y + a2.y + a3.y; awT[1] = w0.y + w1.y + w2.y + w3.y;
    arT[2] = a0.z + a1.z + a2.z + a3.z; awT[2] = w0.z + w1.z + w2.z + w3.z;
    arT[3] = a0.w + a1.w + a2.w + a3.w; awT[3] = w0.w + w1.w + w2.w + w3.w;
    const float invT = 1.0f / NT;
#pragma unroll
    for (int bb = 0; bb < NBATCH; ++bb) {
      float av = fmaf(arT[bb], invT, bfc);
      float wv = fmaf(awT[bb], invT, bfc);
      st[bb] = av * wv;       // num (4x replicated across quads: cancels)
      st[4 + bb] = av * av;   // |ar|^2
      st[8 + bb] = wv * wv;   // |aw|^2
    }
  }
  // block reduction: wave shuffle then LDS combine (4x replication cancels in ratio)
#pragma unroll
  for (int k = 0; k < 12; ++k)
#pragma unroll
    for (int off = 32; off > 0; off >>= 1) st[k] += __shfl_down(st[k], off, 64);
  int wv = tid >> 6, ln = tid & 63;
  if (ln == 0)
#pragma unroll
    for (int k = 0; k < 12; ++k) fin[wv][k] = st[k];
  __syncthreads();
  if (tid < NBATCH) {
    int bb = tid;
    float N = 0.f, A = 0.f, C = 0.f;
    for (int w = 0; w < 16; ++w) {
      N += fin[w][bb];
      A += fin[w][4 + bb];
      C += fin[w][8 + bb];
    }
    out[b0 + bb] = N / fmaxf(sqrtf(A) * sqrtf(C), 1e-8f) * 3.0f;
  }
}

extern "C" void kernel_launch(void* const* d_in, const int* in_sizes, int n_in,
                              void* d_out, int out_size, void* d_ws, size_t ws_size,
                              hipStream_t stream) {
  const float* req  = (const float*)d_in[0];
  const float* wsdl = (const float*)d_in[1];
  const float* TE   = (const float*)d_in[2];
  const float* wf   = (const float*)d_in[3];
  const float* bf   = (const float*)d_in[4];
  float* out = (float*)d_out;

  float* M  = (float*)d_ws;      // 256*256
  float* G2 = M + NT * NT;       // 256*256, pre-scaled by log2(e)
  float* u2 = G2 + NT * NT;      // 256, pre-scaled by log2(e)

  k_M<<<16, 256, 0, stream>>>(TE, wf, M);
  k_G<<<17, 256, 0, stream>>>(M, bf, G2, u2);
  k_main<<<NB / NBATCH, 1024, 0, stream>>>(req, wsdl, M, G2, u2, bf, out);
}

// Round 3
// 152.166 us; speedup vs baseline: 1.1889x; 1.1889x over previous
//
#include <hip/hip_runtime.h>
#include <math.h>

constexpr int NB = 1024;   // batch
constexpr int NT = 256;    // topic_size
constexpr int NE = 300;    // embedding_size
constexpr int NBATCH = 4;  // batches per block
constexpr unsigned GRID = NB / NBATCH;  // 256 blocks, 1 per CU -> co-resident

#if defined(__has_builtin)
#if __has_builtin(__builtin_amdgcn_exp2f)
#define EXP2F(x) __builtin_amdgcn_exp2f(x)
#else
#define EXP2F(x) exp2f(x)
#endif
#if __has_builtin(__builtin_amdgcn_logf)
#define LOG2F(x) __builtin_amdgcn_logf(x)
#else
#define LOG2F(x) log2f(x)
#endif
#else
#define EXP2F(x) exp2f(x)
#define LOG2F(x) log2f(x)
#endif

__device__ __forceinline__ float frag_get(const float4& v, int k) {
  return k == 0 ? v.x : k == 1 ? v.y : k == 2 ? v.z : v.w;
}

// Device-scope grid barrier. Release flushes this block's writes to the
// coherence point (buffer_wbl2 sc1); acquire invalidates stale L1/L2 lines
// (buffer_inv sc1) -> safe across XCDs. Counter zeroed by hipMemsetAsync
// before launch (d_ws is 0xAA-poisoned each call).
__device__ __forceinline__ void grid_barrier(unsigned* cnt, unsigned n) {
  __syncthreads();
  if (threadIdx.x == 0) {
    __hip_atomic_fetch_add(cnt, 1u, __ATOMIC_RELEASE, __HIP_MEMORY_SCOPE_AGENT);
    while (__hip_atomic_load(cnt, __ATOMIC_ACQUIRE, __HIP_MEMORY_SCOPE_AGENT) < n)
      __builtin_amdgcn_s_sleep(2);
  }
  __syncthreads();
}

__global__ __launch_bounds__(1024) void k_fused(
    const float* __restrict__ req, const float* __restrict__ wsdl,
    const float* __restrict__ TE, const float* __restrict__ wf,
    const float* __restrict__ bf, float* __restrict__ out,
    float* __restrict__ Mm, float* __restrict__ G2, float* __restrict__ u2,
    unsigned* __restrict__ bar) {
  __shared__ __align__(16) float L_s[NT][4];
  __shared__ __align__(16) float qv_s[NT][4];
  __shared__ __align__(16) float red[4][NT][8];
  __shared__ float fin[16][12];

  const float LOG2E = 1.4426950408889634f;
  int tid = threadIdx.x;
  int q = __builtin_amdgcn_readfirstlane(tid >> 8);  // quad id, wave-uniform
  int c = tid & 255;
  int blk = blockIdx.x;

  // ================= Phase M: row `blk` of M[t,f] = sum_e TE[e,t]*wf[f,e] ===
  // Quad q covers e-chunks {4q + 16m}. TE reads are wave-uniform -> s_load;
  // wf reads are per-thread float4 row walks (L1-cached lines). No LDS loop.
  {
    float acc = 0.f;
    const float* wrow = wf + c * NE;  // 1200 B stride, 16B aligned
    for (int e4 = q * 4; e4 < NE; e4 += 16) {
      float4 w4 = *(const float4*)(wrow + e4);
      acc = fmaf(TE[(e4 + 0) * NT + blk], w4.x, acc);
      acc = fmaf(TE[(e4 + 1) * NT + blk], w4.y, acc);
      acc = fmaf(TE[(e4 + 2) * NT + blk], w4.z, acc);
      acc = fmaf(TE[(e4 + 3) * NT + blk], w4.w, acc);
    }
    red[q][c][0] = acc;
  }
  __syncthreads();
  if (q == 0)
    Mm[blk * NT + c] = red[0][c][0] + red[1][c][0] + red[2][c][0] + red[3][c][0];
  grid_barrier(bar + 0, GRID);

  // ================= Phase G: row `blk` of G2 = (M M^T)*log2e, u2 = (M bf)*log2e
  {
    float acc = 0.f;
    const float* mi = Mm + blk * NT;  // uniform row -> s_load
    const float* mj = Mm + c * NT;    // per-thread row walk, float4
    for (int k4 = q * 4; k4 < NT; k4 += 16) {
      float4 m4 = *(const float4*)(mj + k4);
      acc = fmaf(mi[k4 + 0], m4.x, acc);
      acc = fmaf(mi[k4 + 1], m4.y, acc);
      acc = fmaf(mi[k4 + 2], m4.z, acc);
      acc = fmaf(mi[k4 + 3], m4.w, acc);
    }
    red[q][c][0] = acc;
  }
  __syncthreads();
  if (q == 0) {
    float g = red[0][c][0] + red[1][c][0] + red[2][c][0] + red[3][c][0];
    G2[blk * NT + c] = g * LOG2E;
    float p = Mm[blk * NT + c] * bf[c];
#pragma unroll
    for (int off = 32; off > 0; off >>= 1) p += __shfl_down(p, off, 64);
    if ((tid & 63) == 0) fin[tid >> 6][0] = p;
  }
  __syncthreads();
  if (tid == 0) u2[blk] = (fin[0][0] + fin[1][0] + fin[2][0] + fin[3][0]) * LOG2E;
  grid_barrier(bar + 1, GRID);

  // ================= Phase main: 4 batches per block ========================
  int i0 = q * 64;
  int b0 = blk * NBATCH;

  // ---- pass 1: per-column (j=c) max over this quad's i-range ----
  float wb[NBATCH], m_loc[NBATCH];
#pragma unroll
  for (int bb = 0; bb < NBATCH; ++bb) {
    wb[bb] = wsdl[(b0 + bb) * NT + c];
    m_loc[bb] = -3.0e38f;
  }
#pragma unroll 8
  for (int ii = 0; ii < 64; ++ii) {
    int i = i0 + ii;
    float g = G2[i * NT + c];  // coalesced
    float su = u2[i];          // uniform -> s_load
#pragma unroll
    for (int bb = 0; bb < NBATCH; ++bb) {
      float sr = req[(b0 + bb) * NT + i];  // uniform -> s_load
      float h = fmaf(wb[bb], g, su);
      m_loc[bb] = fmaxf(m_loc[bb], sr * h);
    }
  }
  *(float4*)&red[q][c][0] = make_float4(m_loc[0], m_loc[1], m_loc[2], m_loc[3]);
  __syncthreads();
  float m_full[NBATCH];
  {
    float4 r0 = *(float4*)&red[0][c][0], r1 = *(float4*)&red[1][c][0];
    float4 r2 = *(float4*)&red[2][c][0], r3 = *(float4*)&red[3][c][0];
    m_full[0] = fmaxf(fmaxf(r0.x, r1.x), fmaxf(r2.x, r3.x));
    m_full[1] = fmaxf(fmaxf(r0.y, r1.y), fmaxf(r2.y, r3.y));
    m_full[2] = fmaxf(fmaxf(r0.z, r1.z), fmaxf(r2.z, r3.z));
    m_full[3] = fmaxf(fmaxf(r0.w, r1.w), fmaxf(r2.w, r3.w));
  }
  __syncthreads();

  // ---- pass 2: denominators; fold to L = m + log2(d) ----
  float d_loc[NBATCH] = {0.f, 0.f, 0.f, 0.f};
#pragma unroll 8
  for (int ii = 0; ii < 64; ++ii) {
    int i = i0 + ii;
    float g = G2[i * NT + c];
    float su = u2[i];
#pragma unroll
    for (int bb = 0; bb < NBATCH; ++bb) {
      float sr = req[(b0 + bb) * NT + i];
      float h = fmaf(wb[bb], g, su);
      d_loc[bb] += EXP2F(fmaf(sr, h, -m_full[bb]));
    }
  }
  *(float4*)&red[q][c][0] = make_float4(d_loc[0], d_loc[1], d_loc[2], d_loc[3]);
  __syncthreads();
  {
    float4 r0 = *(float4*)&red[0][c][0], r1 = *(float4*)&red[1][c][0];
    float4 r2 = *(float4*)&red[2][c][0], r3 = *(float4*)&red[3][c][0];
    if (q == 0) {
      float4 L4;
      L4.x = m_full[0] + LOG2F(r0.x + r1.x + r2.x + r3.x);
      L4.y = m_full[1] + LOG2F(r0.y + r1.y + r2.y + r3.y);
      L4.z = m_full[2] + LOG2F(r0.z + r1.z + r2.z + r3.z);
      L4.w = m_full[3] + LOG2F(r0.w + r1.w + r2.w + r3.w);
      *(float4*)&L_s[c][0] = L4;
    }
  }
  __syncthreads();

  // ---- pass S: row-sums of softmaxed att (row i=c), j over quad range ----
  float rc[NBATCH], Sp[NBATCH] = {0.f, 0.f, 0.f, 0.f};
#pragma unroll
  for (int bb = 0; bb < NBATCH; ++bb) rc[bb] = req[(b0 + bb) * NT + c];
  float uc = u2[c];
#pragma unroll 8
  for (int jj = 0; jj < 64; ++jj) {
    int j = i0 + jj;
    float g = G2[j * NT + c];                // = G2[c][j] by symmetry; coalesced
    float4 Lj = *(const float4*)&L_s[j][0];  // one b128 broadcast per j
#pragma unroll
    for (int bb = 0; bb < NBATCH; ++bb) {
      float sw = wsdl[(b0 + bb) * NT + j];  // uniform -> s_load
      float h = fmaf(sw, g, uc);
      Sp[bb] += EXP2F(fmaf(rc[bb], h, -frag_get(Lj, bb)));
    }
  }
  *(float4*)&red[q][c][0] = make_float4(Sp[0], Sp[1], Sp[2], Sp[3]);
  __syncthreads();
  {
    float4 r0 = *(float4*)&red[0][c][0], r1 = *(float4*)&red[1][c][0];
    float4 r2 = *(float4*)&red[2][c][0], r3 = *(float4*)&red[3][c][0];
    if (q == 0) {
      float4 qv;
      qv.x = (r0.x + r1.x + r2.x + r3.x) * rc[0];
      qv.y = (r0.y + r1.y + r2.y + r3.y) * rc[1];
      qv.z = (r0.z + r1.z + r2.z + r3.z) * rc[2];
      qv.w = (r0.w + r1.w + r2.w + r3.w) * rc[3];
      *(float4*)&qv_s[c][0] = qv;
    }
  }
  __syncthreads();

  // ---- pass B: ave_req = (r/T)@M + bf, ave_wsdl = (qv/T)@M + bf ----
  float ar[NBATCH] = {0.f, 0.f, 0.f, 0.f}, aw[NBATCH] = {0.f, 0.f, 0.f, 0.f};
#pragma unroll 4
  for (int tt = 0; tt < 64; ++tt) {
    int t = i0 + tt;
    float mk = Mm[t * NT + c];  // coalesced
    float4 qv4 = *(const float4*)&qv_s[t][0];
#pragma unroll
    for (int bb = 0; bb < NBATCH; ++bb) {
      float sr = req[(b0 + bb) * NT + t];  // uniform -> s_load
      ar[bb] = fmaf(sr, mk, ar[bb]);
      aw[bb] = fmaf(frag_get(qv4, bb), mk, aw[bb]);
    }
  }
  *(float4*)&red[q][c][0] = make_float4(ar[0], ar[1], ar[2], ar[3]);
  *(float4*)&red[q][c][4] = make_float4(aw[0], aw[1], aw[2], aw[3]);
  __syncthreads();
  float st[12];
  {
    float4 a0 = *(float4*)&red[0][c][0], a1 = *(float4*)&red[1][c][0];
    float4 a2 = *(float4*)&red[2][c][0], a3 = *(float4*)&red[3][c][0];
    float4 w0 = *(float4*)&red[0][c][4], w1 = *(float4*)&red[1][c][4];
    float4 w2 = *(float4*)&red[2][c][4], w3 = *(float4*)&red[3][c][4];
    float bfc = bf[c];
    float arT[4], awT[4];
    arT[0] = a0.x + a1.x + a2.x + a3.x; awT[0] = w0.x + w1.x + w2.x + w3.x;
    arT[1] = a0.y + a1.y + a2.y + a3.y; awT[1] = w0.y + w1.y + w2.y + w3.y;
    arT[2] = a0.z + a1.z + a2.z + a3.z; awT[2] = w0.z + w1.z + w2.z + w3.z;
    arT[3] = a0.w + a1.w + a2.w + a3.w; awT[3] = w0.w + w1.w + w2.w + w3.w;
    const float invT = 1.0f / NT;
#pragma unroll
    for (int bb = 0; bb < NBATCH; ++bb) {
      float av = fmaf(arT[bb], invT, bfc);
      float wv = fmaf(awT[bb], invT, bfc);
      st[bb] = av * wv;       // 4x quad replication cancels in the ratio
      st[4 + bb] = av * av;
      st[8 + bb] = wv * wv;
    }
  }
#pragma unroll
  for (int k = 0; k < 12; ++k)
#pragma unroll
    for (int off = 32; off > 0; off >>= 1) st[k] += __shfl_down(st[k], off, 64);
  int wv = tid >> 6, ln = tid & 63;
  if (ln == 0)
#pragma unroll
    for (int k = 0; k < 12; ++k) fin[wv][k] = st[k];
  __syncthreads();
  if (tid < NBATCH) {
    int bb = tid;
    float N = 0.f, A = 0.f, C = 0.f;
    for (int w = 0; w < 16; ++w) {
      N += fin[w][bb];
      A += fin[w][4 + bb];
      C += fin[w][8 + bb];
    }
    out[b0 + bb] = N / fmaxf(sqrtf(A) * sqrtf(C), 1e-8f) * 3.0f;
  }
}

extern "C" void kernel_launch(void* const* d_in, const int* in_sizes, int n_in,
                              void* d_out, int out_size, void* d_ws, size_t ws_size,
                              hipStream_t stream) {
  const float* req  = (const float*)d_in[0];
  const float* wsdl = (const float*)d_in[1];
  const float* TE   = (const float*)d_in[2];
  const float* wf   = (const float*)d_in[3];
  const float* bf   = (const float*)d_in[4];
  float* out = (float*)d_out;

  // ws layout: [bar: 256 B pad][M: 256*256 f][G2: 256*256 f][u2: 256 f]
  unsigned* bar = (unsigned*)d_ws;
  float* Mm = (float*)((char*)d_ws + 256);
  float* G2 = Mm + NT * NT;
  float* u2 = G2 + NT * NT;

  hipMemsetAsync(bar, 0, 2 * sizeof(unsigned), stream);  // capturable
  k_fused<<<GRID, 1024, 0, stream>>>(req, wsdl, TE, wf, bf, out, Mm, G2, u2, bar);
}